// Round 1
// 231.520 us; speedup vs baseline: 1.0793x; 1.0793x over previous
//
#include <hip/hip_runtime.h>
#include <hip/hip_bf16.h>

#define NN 4096

typedef __attribute__((ext_vector_type(8))) short short8;
typedef __attribute__((ext_vector_type(4))) float f32x4;

// fp32 -> bf16 round-to-nearest-even
static __device__ __forceinline__ unsigned short f2bf(float x) {
    unsigned int u = __float_as_uint(x);
    u += 0x7fffu + ((u >> 16) & 1u);
    return (unsigned short)(u >> 16);
}

// async global->LDS, 16 bytes per lane (dest = wave-uniform base + lane*16)
static __device__ __forceinline__ void load_lds16(const unsigned short* g, unsigned short* l) {
    __builtin_amdgcn_global_load_lds(
        (const __attribute__((address_space(1))) unsigned int*)g,
        (__attribute__((address_space(3))) unsigned int*)l,
        16, 0, 0);
}

// ---------------- fused pre-pass: convA + convB + zero-tiles in ONE launch ----------------
// blocks [0,16384)      : A -> bf16, tril mask (k<=i); skip k-regions the GEMM never reads
// blocks [16384,20480)  : B -> bf16 transposed, mask (k>=j); skip never-read blocks
// blocks [20480,21276)  : zero strict-upper tiles (496) + atomic-partial lower tiles (300)
__global__ __launch_bounds__(256) void prep_all(const float* __restrict__ A,
                                                const float* __restrict__ B,
                                                unsigned short* __restrict__ Abf,
                                                unsigned short* __restrict__ Btb,
                                                float* __restrict__ C) {
    __shared__ float tile[64][65];
    const int b   = blockIdx.x;
    const int tid = threadIdx.x;

    if (b < 16384) {
        // ---- convA ----
        int t   = b * 256 + tid;
        int row = t >> 10;
        int c4  = (t & 1023) << 2;
        // GEMM reads Abf[row][k] only for k < (row_tile+1)*128
        int kmax = ((row >> 7) + 1) << 7;
        if (c4 < kmax) {
            const float4 v = *(const float4*)(A + ((size_t)row << 12) + c4);
            ushort4 o;
            o.x = (c4 + 0 <= row) ? f2bf(v.x) : (unsigned short)0;
            o.y = (c4 + 1 <= row) ? f2bf(v.y) : (unsigned short)0;
            o.z = (c4 + 2 <= row) ? f2bf(v.z) : (unsigned short)0;
            o.w = (c4 + 3 <= row) ? f2bf(v.w) : (unsigned short)0;
            *(ushort4*)(Abf + ((size_t)row << 12) + c4) = o;
        }
    } else if (b < 20480) {
        // ---- convB: Bt[n][k] = (k>=n) ? bf16(B[k][n]) : 0 ----
        const int b2 = b - 16384;
        const int n0 = (b2 & 63) << 6;
        const int k0 = (b2 >> 6) << 6;
        // GEMM reads Btb[n][k] only for k >= (n_tile)*128; k0,n0 64-aligned =>
        // block needed iff k0 >= (n0>>7)<<7
        if (k0 < ((n0 >> 7) << 7)) return;
        #pragma unroll
        for (int p = 0; p < 4; ++p) {
            int idx = p * 256 + tid;
            int kr  = idx >> 4;
            int c4  = (idx & 15) << 2;
            const float4 v = *(const float4*)(B + (size_t)(k0 + kr) * NN + n0 + c4);
            tile[kr][c4 + 0] = v.x; tile[kr][c4 + 1] = v.y;
            tile[kr][c4 + 2] = v.z; tile[kr][c4 + 3] = v.w;
        }
        __syncthreads();
        #pragma unroll
        for (int p = 0; p < 4; ++p) {
            int idx = p * 256 + tid;
            int nr  = idx >> 4;
            int k4  = (idx & 15) << 2;
            int gn  = n0 + nr;
            ushort4 o;
            o.x = (k0 + k4 + 0 >= gn) ? f2bf(tile[k4 + 0][nr]) : (unsigned short)0;
            o.y = (k0 + k4 + 1 >= gn) ? f2bf(tile[k4 + 1][nr]) : (unsigned short)0;
            o.z = (k0 + k4 + 2 >= gn) ? f2bf(tile[k4 + 2][nr]) : (unsigned short)0;
            o.w = (k0 + k4 + 3 >= gn) ? f2bf(tile[k4 + 3][nr]) : (unsigned short)0;
            *(ushort4*)(Btb + (size_t)gn * NN + k0 + k4) = o;
        }
    } else {
        // ---- zero tiles ----
        const int t = b - 20480;
        int bi, bj;
        if (t < 496) {
            int u = t;
            int e = (int)((sqrtf(8.f * (float)u + 1.f) - 1.f) * 0.5f);
            while ((e + 1) * (e + 2) / 2 <= u) ++e;
            while (e * (e + 1) / 2 > u) --e;
            int r = u - e * (e + 1) / 2;
            bi = r; bj = e + 1;
        } else {
            int u = t - 496;
            int d = 8;
            for (; d < 32; ++d) { int cnt = 32 - d; if (u < cnt) break; u -= cnt; }
            bj = u; bi = u + d;
        }
        const float4 z = make_float4(0.f, 0.f, 0.f, 0.f);
        #pragma unroll
        for (int it = 0; it < 16; ++it) {
            int idx = it * 256 + tid;
            int rr  = idx >> 5;
            int c4  = (idx & 31) << 2;
            *(float4*)&C[(size_t)(bi * 128 + rr) * NN + bj * 128 + c4] = z;
        }
    }
}

// ---------------- main GEMM: 128x128 tile, BK=32, split-K, 2-phase dbuf pipeline ----------------
// grid = 1000 units, dispatched LONGEST-WORK-FIRST: unit -> (d, tile, k-chunk), m = ceil((d+1)/8)
__global__ __launch_bounds__(256, 2) void gemm_tril_sk(const unsigned short* __restrict__ Abf,
                                                       const unsigned short* __restrict__ Btb,
                                                       float* __restrict__ C) {
    const int tid = threadIdx.x;

    // reversed enumeration: blockIdx 0 gets the deepest-K units (d=31), diagonal units last
    int u = 999 - (int)blockIdx.x, d, m = 1;
    for (d = 0; d < 32; ++d) {
        m = (d + 8) >> 3;                       // ceil((d+1)/8)
        int cnt = (32 - d) * m;
        if (u < cnt) break;
        u -= cnt;
    }
    const int blk = u / m;
    const int c   = u - blk * m;
    const int bj = blk, bi = blk + d;

    __shared__ __attribute__((aligned(16))) unsigned short As[2][128 * 32];
    __shared__ __attribute__((aligned(16))) unsigned short Bs[2][128 * 32];

    const int lane = tid & 63;
    const int w    = tid >> 6;
    const int wm   = w >> 1, wn = w & 1;
    const int l15  = lane & 15, quad = lane >> 4;

    f32x4 acc[4][4];
    const f32x4 zero4 = {0.f, 0.f, 0.f, 0.f};
    #pragma unroll
    for (int i = 0; i < 4; ++i)
        #pragma unroll
        for (int j = 0; j < 4; ++j) acc[i][j] = zero4;

    const int kbB = (bj << 2) + c * 32;
    const int kbE = min(kbB + 32, (bi << 2) + 4);   // exclusive

    // per-thread staging addresses (ci = u2*256 + tid; rowA = ci>>2, q = ci&3)
    const int rowA = tid >> 2;
    const int q    = tid & 3;
    const unsigned short* Ab = Abf + (size_t)(bi * 128 + rowA) * NN + q * 8;
    const unsigned short* Bb = Btb + (size_t)(bj * 128 + rowA) * NN + q * 8;

    auto STAGE = [&](int buf, int kb) {
        const int koff = kb << 5;
        load_lds16(Ab + koff,                    &As[buf][tid * 8]);
        load_lds16(Bb + koff,                    &Bs[buf][tid * 8]);
        load_lds16(Ab + (size_t)64 * NN + koff,  &As[buf][(256 + tid) * 8]);
        load_lds16(Bb + (size_t)64 * NN + koff,  &Bs[buf][(256 + tid) * 8]);
    };

    auto COMPUTE = [&](int buf) {
        short8 a[4], bf[4];
        #pragma unroll
        for (int mt = 0; mt < 4; ++mt)
            a[mt] = *(const short8*)&As[buf][(wm * 64 + mt * 16 + l15) * 32 + quad * 8];
        #pragma unroll
        for (int nt = 0; nt < 4; ++nt)
            bf[nt] = *(const short8*)&Bs[buf][(wn * 64 + nt * 16 + l15) * 32 + quad * 8];
        #pragma unroll
        for (int mt = 0; mt < 4; ++mt)
            #pragma unroll
            for (int nt = 0; nt < 4; ++nt)
                acc[mt][nt] = __builtin_amdgcn_mfma_f32_16x16x32_bf16(a[mt], bf[nt], acc[mt][nt], 0, 0, 0);
    };

    // 2-phase pipeline: stage(next) issued BEFORE compute(cur); one barrier per K-step.
    // __syncthreads' implicit vmcnt(0) drain is overlapped by the 16 MFMAs of COMPUTE.
    STAGE(0, kbB);
    __syncthreads();
    int cur = 0;
    for (int kb = kbB; kb < kbE - 1; ++kb) {
        STAGE(cur ^ 1, kb + 1);
        COMPUTE(cur);
        __syncthreads();
        cur ^= 1;
    }
    COMPUTE(cur);

    // epilogue: C/D layout col=lane&15, row=quad*4+reg (m89-verified)
    if (m == 1) {
        #pragma unroll
        for (int mt = 0; mt < 4; ++mt) {
            #pragma unroll
            for (int nt = 0; nt < 4; ++nt) {
                const int gj  = bj * 128 + wn * 64 + nt * 16 + l15;
                const int gi0 = bi * 128 + wm * 64 + mt * 16 + quad * 4;
                #pragma unroll
                for (int rr = 0; rr < 4; ++rr) {
                    int gi = gi0 + rr;
                    float v = acc[mt][nt][rr];
                    C[(size_t)gi * NN + gj] = (d > 0 || gi >= gj) ? v : 0.f;
                }
            }
        }
    } else {
        // partial contribution: tile was pre-zeroed; d>=8 so strictly lower, no mask
        #pragma unroll
        for (int mt = 0; mt < 4; ++mt) {
            #pragma unroll
            for (int nt = 0; nt < 4; ++nt) {
                const int gj  = bj * 128 + wn * 64 + nt * 16 + l15;
                const int gi0 = bi * 128 + wm * 64 + mt * 16 + quad * 4;
                #pragma unroll
                for (int rr = 0; rr < 4; ++rr) {
                    int gi = gi0 + rr;
                    atomicAdd(&C[(size_t)gi * NN + gj], acc[mt][nt][rr]);
                }
            }
        }
    }
}

// ---------------- fallback (ws too small): fp32 LDS-tiled, correct-but-slow ----------------
__global__ void gemm_fallback(const float* __restrict__ A, const float* __restrict__ B,
                              float* __restrict__ C) {
    const int bi = blockIdx.y, bj = blockIdx.x;
    const int ty = threadIdx.y, tx = threadIdx.x;
    const int gi = bi * 32 + ty, gj = bj * 32 + tx;
    if (bi < bj) { C[(size_t)gi * NN + gj] = 0.f; return; }
    __shared__ float As[32][33], Bs[32][33];
    float s = 0.f;
    for (int kt = bj; kt <= bi; ++kt) {
        const int k = kt * 32;
        float av = A[(size_t)gi * NN + k + tx];
        As[ty][tx] = (k + tx <= gi) ? av : 0.f;
        float bv = B[(size_t)(k + ty) * NN + gj];
        Bs[ty][tx] = (k + ty >= gj) ? bv : 0.f;
        __syncthreads();
        #pragma unroll
        for (int kk = 0; kk < 32; ++kk) s += As[ty][kk] * Bs[kk][tx];
        __syncthreads();
    }
    C[(size_t)gi * NN + gj] = (gi >= gj) ? s : 0.f;
}

extern "C" void kernel_launch(void* const* d_in, const int* in_sizes, int n_in,
                              void* d_out, int out_size, void* d_ws, size_t ws_size,
                              hipStream_t stream) {
    const float* A = (const float*)d_in[0];
    const float* B = (const float*)d_in[1];
    float* C = (float*)d_out;

    const size_t need = (size_t)2 * NN * NN * sizeof(unsigned short);  // 64 MB
    if (ws_size >= need) {
        unsigned short* Abf = (unsigned short*)d_ws;
        unsigned short* Btb = Abf + (size_t)NN * NN;
        prep_all<<<dim3(21276), dim3(256), 0, stream>>>(A, B, Abf, Btb, C);
        gemm_tril_sk<<<dim3(1000), dim3(256), 0, stream>>>(Abf, Btb, C);
    } else {
        gemm_fallback<<<dim3(128, 128), dim3(32, 32), 0, stream>>>(A, B, C);
    }
}